// Round 5
// baseline (163.355 us; speedup 1.0000x reference)
//
#include <hip/hip_runtime.h>
#include <math.h>

// ---------------------------------------------------------------------------
// TwoDimEquivalent: B=8192 independent nonlinear scans of length T=2048.
//  * gauss_int depends only on s = delta^2 -> float2 pair-LUT in LDS
//    (one ds_read_b64 per step; LUT = exact 64-pt GL sum, nodes via Newton).
//  * 16 chunks x 128 steps, 128-step warmup (contraction ~0.93/step).
//  * ILP-2 (R10): each thread advances TWO rows; both per-step ds_read_b64
//    gathers issue back-to-back so their ~120+cyc latencies overlap in one
//    stall window (chain was the 170-of-250-cyc/step stall in R9; chains/
//    SIMD unchanged at 2: grid 256 x 4 waves = 1 wave/SIMD x 2 chains).
//  * Counted barriers (R9 fix, kept): raw s_barrier + lgkmcnt(0); vmcnt
//    never drained -> prefetch loads stay in flight across barriers.
//  * u reads: float4, depth-2 register prefetch (4 cur + 4 nxt float4).
//  * LDS: 16 KB tab + overlay{staging s_u2[4][512] 16 KB, transpose tile
//    s_zt[256][33] 33 KB} = 50 KB; never live simultaneously.
//  * z output: zz_a[32]+zz_b[32] regs per quarter-chunk, flushed via
//    [256][33] tile (write (tid+j)%32 banks, read 2 lanes/bank: free),
//    128 B contiguous row segments.
// History: R5 151.9 graded (cold 147.6 / warm 57). R7 chunks=32: BW-bound
// regress. R8 LLC-touch: rocprof-cold fast, graded unmoved. R9 counted
// barriers: rocprof-cold 58.6 (fix confirmed) but graded 150 -> graded runs
// in a ~2.5x-degraded regime (DVFS/cold env); graded ~ 2.5 x warm + setup.
// => R10 attacks warm: ILP-2 latency pairing. Predict warm 36-45,
// graded 95-115; if warm ~57 unchanged, limiter is LDS pipe, not latency.
// ---------------------------------------------------------------------------

#define Bsz   8192
#define Tlen  2048
#define TP1   2049
#define NQ    64
#define NG    2049                // scalar g samples, s = j/32 on [0,64]
#define NTAB2 2048                // float2 pair entries (16 KB)
#define INV_H 32.0f
#define CHUNKS 16
#define CLEN  128
#define WARM  128
#define BLOCK 256
#define ROWS_PB 512               // rows per block (2 per thread)
#define NRB   16                  // row-blocks
#define SIM_GRID (NRB * CHUNKS)   // 256

#define WS_TAB 128                // scalar g table offset (floats) in d_ws

// Raw barrier: LDS-visibility only, vmcnt NOT drained (prefetch stays live).
__device__ __forceinline__ void bar_nodrain() {
    asm volatile("s_waitcnt lgkmcnt(0)" ::: "memory");
    __builtin_amdgcn_s_barrier();
}

// --------------------------- setup: build LUT ------------------------------
__global__ __launch_bounds__(256) void setup_kernel(float* __restrict__ ws,
                                                    float* __restrict__ out) {
    __shared__ float  fx[NQ], fw[NQ];
    __shared__ double inv[NQ + 1];
    const int tid = threadIdx.x;
    if (tid <= NQ) inv[tid] = (tid == 0) ? 0.0 : 1.0 / (double)tid;
    __syncthreads();
    if (tid < NQ) {
        // Newton on P_64: guess err ~3e-4 -> 3 updates reach ~1e-15,
        // 4th pass evaluates pp at converged z (no update).
        double z = cos(3.14159265358979323846 * (tid + 0.75) / (NQ + 0.5));
        double p1 = 1.0, p2 = 0.0, pp = 1.0;
        for (int it = 0; it < 4; ++it) {
            p1 = 1.0; p2 = 0.0;
            for (int j = 1; j <= NQ; ++j) {
                double p3 = p2; p2 = p1;
                p1 = ((2.0 * j - 1.0) * z * p2 - (j - 1.0) * p3) * inv[j];
            }
            pp = NQ * (z * p1 - p2) / (z * z - 1.0);
            if (it < 3) z -= p1 / pp;
        }
        double w  = 2.0 / ((1.0 - z * z) * pp * pp);
        double xs = z * 5.0;                       // node scaled to [-5,5]
        fx[tid] = (float)xs;                       // f32 cast, like reference
        fw[tid] = (float)(w * 5.0 * exp(-0.5 * xs * xs) * 0.3989422804014327);
    }
    __syncthreads();
    const int j = blockIdx.x * 256 + tid;          // grid 32x256 = 8192
    if (j < NG) {                                  // g(s_j), s_j = j/32
        const float d = sqrtf((float)j * (1.0f / INV_H));
        float acc = 0.0f;
        #pragma unroll 8
        for (int q = 0; q < NQ; ++q) {
            float t = tanhf(d * fx[q]);
            acc = fmaf(fw[q], 1.0f - t * t, acc);
        }
        ws[WS_TAB + j] = acc;
    }
    out[(size_t)j * TP1] = 0.0f;                   // z_hist[:,0] = 0
}

// ------------------------------ main scan ----------------------------------
// Two independent rows per call: both ds_read_b64 issue before either use,
// overlapping their latencies in one stall window (the ILP-2 point).
__device__ __forceinline__ void step_pair(float uA, float uB,
                                          float& k1A, float& k2A, float& vA,
                                          float& k1B, float& k2B, float& vB,
                                          const float2* s_tab,
                                          float& zA, float& zB) {
    float sA   = fmaf(k1A, k1A, fmaf(k2A, k2A, uA * uA));
    float sB   = fmaf(k1B, k1B, fmaf(k2B, k2B, uB * uB));
    float idxA = fminf(sA * INV_H, 2046.999f);
    float idxB = fminf(sB * INV_H, 2046.999f);
    int   i0A  = (int)idxA;
    int   i0B  = (int)idxB;
    float2 gA  = s_tab[i0A];                       // two ds_read_b64,
    float2 gB  = s_tab[i0B];                       // latencies overlap
    float fA   = idxA - (float)i0A;
    float fB   = idxB - (float)i0B;
    float gxA  = fmaf(fA, gA.y - gA.x, gA.x);
    float gxB  = fmaf(fB, gB.y - gB.x, gB.x);
    float gvA  = gxA * vA;
    float gvB  = gxB * vB;
    float nk1A = fmaf(k1A, fmaf(0.2f, gxA, 0.8f), 0.10f * gvA);
    float nk1B = fmaf(k1B, fmaf(0.2f, gxB, 0.8f), 0.10f * gvB);
    float nk2A = fmaf(k2A, fmaf(0.1f, gxA, 0.8f), 0.38f * gvA);
    float nk2B = fmaf(k2B, fmaf(0.1f, gxB, 0.8f), 0.38f * gvB);
    vA = fmaf(0.2f, uA - vA, vA);
    vB = fmaf(0.2f, uB - vB, vB);
    k1A = nk1A; k2A = nk2A;
    k1B = nk1B; k2B = nk2B;
    zA = fmaf(2.8f, nk1A, -2.2f * nk2A);
    zB = fmaf(2.8f, nk1B, -2.2f * nk2B);
}

__global__ __launch_bounds__(BLOCK, 1) void sim_kernel(const float* __restrict__ u,
                                                       const float* __restrict__ ws,
                                                       float* __restrict__ out) {
    __shared__ float2 s_tab[NTAB2];                      // 16 KB pair table
    __shared__ __align__(16) char s_ovl[256 * 33 * 4];   // 33 KB overlay
    float2 (*s_u2)[ROWS_PB] = (float2 (*)[ROWS_PB])s_ovl;  // staging view
    float* s_zt = (float*)s_ovl;                         // transpose view
    const int tid = threadIdx.x;

    const int c    = blockIdx.x >> 4;              // chunk id (16)
    const int bb   = blockIdx.x & 15;              // row-block id (16)
    const int rowb = bb * ROWS_PB;
    const int t_out   = c * CLEN;                  // first owned step
    const int t_begin = (t_out >= WARM) ? (t_out - WARM) : 0;   // c=0 -> 0

    const int r1 = tid >> 1;                       // 0..127
    const int h4 = (tid & 1) * 4;
    const int ph = (tid & 1) * 2;
    const float* __restrict__ upb = u + (size_t)(rowb + r1) * Tlen + h4;
    const int RO = 128 * Tlen;                     // 128-row pointer stride

    // Issue the 8 pipeline loads FIRST so cold misses start immediately.
    float4 A0 = *(const float4*)(upb + t_begin);
    float4 A1 = *(const float4*)(upb + t_begin + RO);
    float4 A2 = *(const float4*)(upb + t_begin + 2 * RO);
    float4 A3 = *(const float4*)(upb + t_begin + 3 * RO);
    float4 B0 = *(const float4*)(upb + t_begin + 8);
    float4 B1 = *(const float4*)(upb + t_begin + 8 + RO);
    float4 B2 = *(const float4*)(upb + t_begin + 8 + 2 * RO);
    float4 B3 = *(const float4*)(upb + t_begin + 8 + 3 * RO);

    {   // pair-table fill from scalar g[] in ws (coalesced float4 + 1 scalar)
        const float* g = ws + WS_TAB;
        #pragma unroll
        for (int i = 0; i < NTAB2 / (BLOCK * 4); ++i) {   // 2 iters
            int k = (i * BLOCK + tid) * 4;
            float4 a = *(const float4*)(g + k);
            float  b = g[k + 4];
            s_tab[k + 0] = make_float2(a.x, a.y);
            s_tab[k + 1] = make_float2(a.y, a.z);
            s_tab[k + 2] = make_float2(a.z, a.w);
            s_tab[k + 3] = make_float2(a.w, b);
        }
    }

    float k1A = 0.f, k2A = 0.f, vA = 0.f;          // row rowb+tid
    float k1B = 0.f, k2B = 0.f, vB = 0.f;          // row rowb+tid+256

    // ---------------- warmup: state only, z discarded ----------------
    for (int tb = t_begin; tb < t_out; tb += 8) {
        bar_nodrain();                             // s_u2 free
        s_u2[ph    ][r1      ] = make_float2(A0.x, A0.y);
        s_u2[ph + 1][r1      ] = make_float2(A0.z, A0.w);
        s_u2[ph    ][r1 + 128] = make_float2(A1.x, A1.y);
        s_u2[ph + 1][r1 + 128] = make_float2(A1.z, A1.w);
        s_u2[ph    ][r1 + 256] = make_float2(A2.x, A2.y);
        s_u2[ph + 1][r1 + 256] = make_float2(A2.z, A2.w);
        s_u2[ph    ][r1 + 384] = make_float2(A3.x, A3.y);
        s_u2[ph + 1][r1 + 384] = make_float2(A3.z, A3.w);
        A0 = B0; A1 = B1; A2 = B2; A3 = B3;
        const int tn = tb + 16;                    // <= t_out+8 <= 1928, safe
        B0 = *(const float4*)(upb + tn);
        B1 = *(const float4*)(upb + tn + RO);
        B2 = *(const float4*)(upb + tn + 2 * RO);
        B3 = *(const float4*)(upb + tn + 3 * RO);
        bar_nodrain();                             // s_u2 ready
        float zs0, zs1;                            // discarded
        #pragma unroll
        for (int p = 0; p < 4; ++p) {
            float2 ua = s_u2[p][tid];
            float2 ub = s_u2[p][tid + 256];
            step_pair(ua.x, ub.x, k1A, k2A, vA, k1B, k2B, vB, s_tab, zs0, zs1);
            step_pair(ua.y, ub.y, k1A, k2A, vA, k1B, k2B, vB, s_tab, zs0, zs1);
        }
    }

    // ---------------- output: four quarter-chunks of 32 steps --------------
    const int col = tid & 31;                      // flush store lane->col
    const int rq  = tid >> 5;                      // flush store row quad (0..7)
    for (int q = 0; q < 4; ++q) {
        float zz_a[32], zz_b[32];                  // rows tid / tid+256
        #pragma unroll
        for (int it4 = 0; it4 < 4; ++it4) {
            const int tb = t_out + q * 32 + it4 * 8;
            bar_nodrain();                         // s_u2 free
            s_u2[ph    ][r1      ] = make_float2(A0.x, A0.y);
            s_u2[ph + 1][r1      ] = make_float2(A0.z, A0.w);
            s_u2[ph    ][r1 + 128] = make_float2(A1.x, A1.y);
            s_u2[ph + 1][r1 + 128] = make_float2(A1.z, A1.w);
            s_u2[ph    ][r1 + 256] = make_float2(A2.x, A2.y);
            s_u2[ph + 1][r1 + 256] = make_float2(A2.z, A2.w);
            s_u2[ph    ][r1 + 384] = make_float2(A3.x, A3.y);
            s_u2[ph + 1][r1 + 384] = make_float2(A3.z, A3.w);
            A0 = B0; A1 = B1; A2 = B2; A3 = B3;
            int tn = tb + 16;                      // clamp: tail of c=15
            if (tn > Tlen - 8) tn = Tlen - 8;
            B0 = *(const float4*)(upb + tn);
            B1 = *(const float4*)(upb + tn + RO);
            B2 = *(const float4*)(upb + tn + 2 * RO);
            B3 = *(const float4*)(upb + tn + 3 * RO);
            bar_nodrain();                         // s_u2 ready
            #pragma unroll
            for (int p = 0; p < 4; ++p) {
                float2 ua = s_u2[p][tid];
                float2 ub = s_u2[p][tid + 256];
                step_pair(ua.x, ub.x, k1A, k2A, vA, k1B, k2B, vB, s_tab,
                          zz_a[it4 * 8 + 2 * p    ], zz_b[it4 * 8 + 2 * p    ]);
                step_pair(ua.y, ub.y, k1A, k2A, vA, k1B, k2B, vB, s_tab,
                          zz_a[it4 * 8 + 2 * p + 1], zz_b[it4 * 8 + 2 * p + 1]);
            }
        }
        // ---- flush quarter q: 2 phases x (256 rows x 32 cols) ----
        const int cb = t_out + 1 + q * 32;         // first output col
        bar_nodrain();                             // s_u2 reads consumed
        #pragma unroll
        for (int j = 0; j < 32; ++j)               // banks (tid+j)%32: free
            s_zt[tid * 33 + j] = zz_a[j];
        bar_nodrain();                             // tile A ready
        #pragma unroll
        for (int k = 0; k < 32; ++k) {
            int row = k * 8 + rq;                  // 0..255
            out[(size_t)(rowb + row) * TP1 + cb + col] = s_zt[row * 33 + col];
        }
        bar_nodrain();                             // tile free (reads retired)
        #pragma unroll
        for (int j = 0; j < 32; ++j)
            s_zt[tid * 33 + j] = zz_b[j];
        bar_nodrain();                             // tile B ready
        #pragma unroll
        for (int k = 0; k < 32; ++k) {
            int row = k * 8 + rq;
            out[(size_t)(rowb + 256 + row) * TP1 + cb + col] = s_zt[row * 33 + col];
        }
    }
}

// ------------------------------ launcher -----------------------------------
extern "C" void kernel_launch(void* const* d_in, const int* in_sizes, int n_in,
                              void* d_out, int out_size, void* d_ws, size_t ws_size,
                              hipStream_t stream) {
    const float* u = (const float*)d_in[0];
    float* out = (float*)d_out;
    float* ws  = (float*)d_ws;                     // needs ~9 KB
    setup_kernel<<<32, 256, 0, stream>>>(ws, out);
    sim_kernel<<<SIM_GRID, BLOCK, 0, stream>>>(u, ws, out);
}

// Round 6
// 144.982 us; speedup vs baseline: 1.1267x; 1.1267x over previous
//
#include <hip/hip_runtime.h>
#include <math.h>

// ---------------------------------------------------------------------------
// TwoDimEquivalent: B=8192 independent nonlinear scans of length T=2048.
// R11: WAVE-AUTONOMOUS scanning -- no s_barrier in the main loop.
//  * Each wave owns 64 rows (1/lane) and stages its own u window (32 steps)
//    into a PRIVATE LDS buffer [64][33] via 8 coalesced 128-B-segment loads
//    + 32 ds_write_b32; intra-wave ordering via lgkmcnt(0) only (DS pipe is
//    in-order per wave). Eliminates the block-wide lockstep that inflated
//    the ~170-cyc serial chain to 267 cyc/step (R9) and the TLP loss that
//    made ILP-2 regress (R10: 1 wave/SIMD -> 332 cyc/step).
//  * 2048 independent waves = 2/SIMD free-running chains.
//  * gauss_int: s = delta^2 -> float2 pair-LUT in LDS (one ds_read_b64/step).
//  * 16 chunks x 128 steps, 128-step warmup (bytes identical to R9).
//  * u prefetch: next window's 8 float4 loads issued while current window
//    computes (~5400 cyc cover); vmcnt never force-drained (no barriers).
//  * z: zz[64] regs, flushed per 64 steps via the SAME per-wave LDS buffer
//    (two 32-col transpose passes, adjacent in time -> L2 write-combine),
//    128-B contiguous row segments, banks 2-way (free) throughout.
//  * LDS: 16 KB tab + 4x8.4 KB wave buffers = 50 KB -> 2 blocks/CU (grid
//    512), 8 waves/CU.
// History: R5 151.9 (warm 57). R7 chunks=32: +bytes regress. R8 LLC-touch:
// graded unmoved -> graded runs ~2.5x-degraded (env/DVFS); optimize warm.
// R9 counted barriers: rocprof-cold 58.6 fixed. R10 ILP-2: TLP loss, 332
// cyc/step. R11 predict: warm 28-38, graded 75-95; if warm >=50 -> LDS pipe.
// ---------------------------------------------------------------------------

#define Bsz   8192
#define Tlen  2048
#define TP1   2049
#define NQ    64
#define NG    2049                // scalar g samples, s = j/32 on [0,64]
#define NTAB2 2048                // float2 pair entries (16 KB)
#define INV_H 32.0f
#define CHUNKS 16
#define CLEN  128
#define WARM  128
#define BLOCK 256
#define SIM_GRID (32 * CHUNKS)    // 512: 32 row-blocks(256) x 16 chunks
#define SROW  33                  // staging row stride (floats)

#define WS_TAB 128                // scalar g table offset (floats) in d_ws

// LDS-visibility barrier (setup only); vmcnt NOT drained.
__device__ __forceinline__ void bar_nodrain() {
    asm volatile("s_waitcnt lgkmcnt(0)" ::: "memory");
    __builtin_amdgcn_s_barrier();
}
// Intra-wave DS fence: all my ds ops complete, compiler may not reorder.
__device__ __forceinline__ void ds_fence() {
    asm volatile("s_waitcnt lgkmcnt(0)" ::: "memory");
}

// --------------------------- setup: build LUT ------------------------------
__global__ __launch_bounds__(256) void setup_kernel(float* __restrict__ ws,
                                                    float* __restrict__ out) {
    __shared__ float  fx[NQ], fw[NQ];
    __shared__ double inv[NQ + 1];
    const int tid = threadIdx.x;
    if (tid <= NQ) inv[tid] = (tid == 0) ? 0.0 : 1.0 / (double)tid;
    __syncthreads();
    if (tid < NQ) {
        // Newton on P_64: guess err ~3e-4 -> 3 updates reach ~1e-15,
        // 4th pass evaluates pp at converged z (no update).
        double z = cos(3.14159265358979323846 * (tid + 0.75) / (NQ + 0.5));
        double p1 = 1.0, p2 = 0.0, pp = 1.0;
        for (int it = 0; it < 4; ++it) {
            p1 = 1.0; p2 = 0.0;
            for (int j = 1; j <= NQ; ++j) {
                double p3 = p2; p2 = p1;
                p1 = ((2.0 * j - 1.0) * z * p2 - (j - 1.0) * p3) * inv[j];
            }
            pp = NQ * (z * p1 - p2) / (z * z - 1.0);
            if (it < 3) z -= p1 / pp;
        }
        double w  = 2.0 / ((1.0 - z * z) * pp * pp);
        double xs = z * 5.0;                       // node scaled to [-5,5]
        fx[tid] = (float)xs;                       // f32 cast, like reference
        fw[tid] = (float)(w * 5.0 * exp(-0.5 * xs * xs) * 0.3989422804014327);
    }
    __syncthreads();
    const int j = blockIdx.x * 256 + tid;          // grid 32x256 = 8192
    if (j < NG) {                                  // g(s_j), s_j = j/32
        const float d = sqrtf((float)j * (1.0f / INV_H));
        float acc = 0.0f;
        #pragma unroll 8
        for (int q = 0; q < NQ; ++q) {
            float t = tanhf(d * fx[q]);
            acc = fmaf(fw[q], 1.0f - t * t, acc);
        }
        ws[WS_TAB + j] = acc;
    }
    out[(size_t)j * TP1] = 0.0f;                   // z_hist[:,0] = 0
}

// ------------------------------ main scan ----------------------------------
__device__ __forceinline__ float step_one(float uu, float& k1, float& k2,
                                          float& v, const float2* s_tab) {
    float s   = fmaf(k1, k1, fmaf(k2, k2, uu * uu));      // delta^2
    float idx = fminf(s * INV_H, 2046.999f);
    int   i0  = (int)idx;
    float f   = idx - (float)i0;
    float2 g2 = s_tab[i0];                                // one ds_read_b64
    float g   = fmaf(f, g2.y - g2.x, g2.x);               // gauss_int
    float gv  = g * v;
    float nk1 = fmaf(k1, fmaf(0.2f, g, 0.8f), 0.10f * gv);
    float nk2 = fmaf(k2, fmaf(0.1f, g, 0.8f), 0.38f * gv);
    v  = fmaf(0.2f, uu - v, v);
    k1 = nk1; k2 = nk2;
    return fmaf(2.8f, nk1, -2.2f * nk2);
}

// Load next window (8 float4 = 8 rows x 128 B coalesced segments)
#define GLOAD(G, t) { _Pragma("unroll")                                       \
    for (int r = 0; r < 8; ++r)                                               \
        G[r] = *(const float4*)(up + (size_t)r * 8 * Tlen + (t)); }

// Stage window into per-wave LDS buffer (32 ds_write_b32, banks 2-way free)
#define STAGE(G) { asm volatile("" ::: "memory");  _Pragma("unroll")          \
    for (int r = 0; r < 8; ++r) {                                             \
        int b8 = (8 * r + srow) * SROW + scol;                                \
        sb[b8] = G[r].x; sb[b8+1] = G[r].y; sb[b8+2] = G[r].z;                \
        sb[b8+3] = G[r].w; }                                                  \
    ds_fence(); }

__global__ __launch_bounds__(BLOCK, 2) void sim_kernel(const float* __restrict__ u,
                                                       const float* __restrict__ ws,
                                                       float* __restrict__ out) {
    __shared__ float2 s_tab[NTAB2];                // 16 KB pair table
    __shared__ float  s_st[4][64 * SROW];          // 4 x 8.4 KB per-wave bufs
    const int tid = threadIdx.x;
    const int w   = tid >> 6;                      // wave id (4)
    const int l   = tid & 63;                      // lane
    float* sb = s_st[w];

    const int c    = blockIdx.x >> 5;              // chunk id (16)
    const int bb   = blockIdx.x & 31;              // row-block id (32)
    const int rowb = bb * 256 + w * 64;            // wave's first row
    const int t_out   = c * CLEN;                  // first owned step
    const int t_begin = (t_out >= WARM) ? (t_out - WARM) : 0;   // c=0 -> 0

    // staging lane map: lane l covers row srow of each 8-row group,
    // 16 B at float offset scol within the 32-step window
    const int srow = l >> 3;                       // 0..7
    const int scol = (l & 7) * 4;                  // 0,4,...,28
    const float* __restrict__ up = u + (size_t)(rowb + srow) * Tlen + scol;
    const int lbase = l * SROW;

    // Issue the first two windows FIRST so cold misses start immediately.
    float4 G0[8], G1[8];
    GLOAD(G0, t_begin);
    GLOAD(G1, t_begin + 32);

    {   // pair-table fill from scalar g[] in ws (coalesced float4 + 1 scalar)
        const float* g = ws + WS_TAB;
        #pragma unroll
        for (int i = 0; i < NTAB2 / (BLOCK * 4); ++i) {   // 2 iters
            int k = (i * BLOCK + tid) * 4;
            float4 a = *(const float4*)(g + k);
            float  b = g[k + 4];
            s_tab[k + 0] = make_float2(a.x, a.y);
            s_tab[k + 1] = make_float2(a.y, a.z);
            s_tab[k + 2] = make_float2(a.z, a.w);
            s_tab[k + 3] = make_float2(a.w, b);
        }
    }
    bar_nodrain();                                 // the ONLY block barrier

    float k1 = 0.f, k2 = 0.f, v = 0.f;

    // ---------------- warmup: 0 or 4 windows, z discarded ----------------
    for (int tb = t_begin; tb + 64 <= t_out; tb += 64) {
        // window tb (from G0); prefetch tb+64 into G0
        STAGE(G0);
        GLOAD(G0, tb + 64);
        #pragma unroll
        for (int t2 = 0; t2 < 32; ++t2)
            step_one(sb[lbase + t2], k1, k2, v, s_tab);
        // window tb+32 (from G1); prefetch tb+96 into G1
        STAGE(G1);
        GLOAD(G1, tb + 96);
        #pragma unroll
        for (int t2 = 0; t2 < 32; ++t2)
            step_one(sb[lbase + t2], k1, k2, v, s_tab);
    }

    // ---------------- output: two halves of 64 steps ----------------
    const int col = l & 31;                        // flush col lane
    const int rh  = l >> 5;                        // flush row half (0/1)
    for (int h = 0; h < 2; ++h) {
        float zz[64];
        const int tb = t_out + h * 64;
        {   // window tb (G0); prefetch tb+64 (clamped) into G0
            STAGE(G0);
            int tn = tb + 64; if (tn > Tlen - 32) tn = Tlen - 32;
            GLOAD(G0, tn);
            #pragma unroll
            for (int t2 = 0; t2 < 32; ++t2)
                zz[t2] = step_one(sb[lbase + t2], k1, k2, v, s_tab);
        }
        {   // window tb+32 (G1); prefetch tb+96 (clamped) into G1
            STAGE(G1);
            int tn = tb + 96; if (tn > Tlen - 32) tn = Tlen - 32;
            GLOAD(G1, tn);
            #pragma unroll
            for (int t2 = 0; t2 < 32; ++t2)
                zz[32 + t2] = step_one(sb[lbase + t2], k1, k2, v, s_tab);
        }
        // flush 64 rows x 64 cols via sb, two 32-col transpose passes
        const int cb = t_out + 1 + h * 64;
        #pragma unroll
        for (int p = 0; p < 2; ++p) {
            asm volatile("" ::: "memory");
            #pragma unroll
            for (int j = 0; j < 32; ++j)           // banks (l+j)%32: 2-way
                sb[lbase + j] = zz[p * 32 + j];
            ds_fence();                            // tile ready
            #pragma unroll
            for (int k = 0; k < 32; ++k) {         // 2 rows x 128 B / instr
                int row = 2 * k + rh;
                out[(size_t)(rowb + row) * TP1 + cb + p * 32 + col] =
                    sb[row * SROW + col];
            }
            ds_fence();                            // reads done before reuse
        }
    }
}

// ------------------------------ launcher -----------------------------------
extern "C" void kernel_launch(void* const* d_in, const int* in_sizes, int n_in,
                              void* d_out, int out_size, void* d_ws, size_t ws_size,
                              hipStream_t stream) {
    const float* u = (const float*)d_in[0];
    float* out = (float*)d_out;
    float* ws  = (float*)d_ws;                     // needs ~9 KB
    setup_kernel<<<32, 256, 0, stream>>>(ws, out);
    sim_kernel<<<SIM_GRID, BLOCK, 0, stream>>>(u, ws, out);
}